// Round 2
// baseline (63.298 us; speedup 1.0000x reference)
//
#include <hip/hip_runtime.h>
#include <float.h>
#include <limits.h>
#include <math.h>

// Fixed problem shapes
constexpr int kB = 24;
constexpr int kC = 4;
constexpr int kHW = 65536;              // 256*256
constexpr int kD = 64;
constexpr int kNChunk = 32;
constexpr int kChunk = kHW / kNChunk;   // 2048 pixels per chunk-block
constexpr int kMaxS = 8;                // supports sample_num <= 8 (actual 5)
constexpr float kTau = 0.07f;
constexpr float kEpsLog = 1e-6f;
constexpr float kEpsDen = 1e-8f;
constexpr float kEpsNorm = 1e-12f;

// ---- packed ordering key: high32 = monotone-mapped float (desc), low32 = ~pix (idx asc) ----
__device__ __forceinline__ unsigned long long packKey(float v, unsigned int pix) {
    unsigned int x = __float_as_uint(v);
    unsigned int m = (x & 0x80000000u) ? ~x : (x | 0x80000000u);  // order-preserving map
    return ((unsigned long long)m << 32) | (unsigned long long)(~pix);
}

__device__ __forceinline__ unsigned long long u64max(unsigned long long a, unsigned long long b) {
    return a > b ? a : b;
}

__device__ __forceinline__ unsigned long long shfl_xor_u64(unsigned long long k, int m) {
    int lo = __shfl_xor((int)(unsigned int)k, m, 64);
    int hi = __shfl_xor((int)(unsigned int)(k >> 32), m, 64);
    return ((unsigned long long)(unsigned int)hi << 32) | (unsigned long long)(unsigned int)lo;
}

__device__ __forceinline__ unsigned long long waveMax64(unsigned long long k) {
    #pragma unroll
    for (int o = 32; o > 0; o >>= 1) k = u64max(k, shfl_xor_u64(k, o));
    return k;
}

__device__ __forceinline__ float wave_sum(float x) {
    #pragma unroll
    for (int o = 32; o > 0; o >>= 1) x += __shfl_xor(x, o, 64);
    return x;
}

// ---------------------------------------------------------------------------
// Single fused kernel. grid = kB*kNChunk blocks x 256 threads.
// Phase A (all blocks): uncertainty + hierarchical top-8 of this chunk.
// Phase B (last block per batch): merge 256 candidates, gather 3xS vectors,
//         compute contrastive loss -> per_b[b].
// Phase C (last merger overall): deterministic serial sum -> out[0].
// ---------------------------------------------------------------------------
__global__ __launch_bounds__(256) void k_fused(
        const float* __restrict__ pred, const float* __restrict__ proj,
        const int* __restrict__ idxp, const int* __restrict__ snum,
        unsigned int* __restrict__ batch_ctr, unsigned int* __restrict__ done_ctr,
        unsigned long long* __restrict__ cand, float* __restrict__ per_b,
        float* __restrict__ out) {
    int S = snum[0];
    S = S < 1 ? 1 : (S > kMaxS ? kMaxS : S);
    const int t = threadIdx.x;
    const int lane = t & 63;
    const int wave = t >> 6;
    const int b = blockIdx.x / kNChunk;
    const int chunk = blockIdx.x % kNChunk;
    const int j0 = chunk * kChunk + t * 8;              // 8 consecutive pixels/thread
    const float* pb = pred + (size_t)b * kC * kHW + j0;

    // ---- uncertainty u[j] = sum_c x*log(x+eps) for my 8 pixels ----
    float u[8];
    #pragma unroll
    for (int i = 0; i < 8; ++i) u[i] = 0.f;
    #pragma unroll
    for (int c = 0; c < kC; ++c) {
        float4 a = *reinterpret_cast<const float4*>(pb + (size_t)c * kHW);
        float4 d = *reinterpret_cast<const float4*>(pb + (size_t)c * kHW + 4);
        u[0] += a.x * __logf(a.x + kEpsLog);
        u[1] += a.y * __logf(a.y + kEpsLog);
        u[2] += a.z * __logf(a.z + kEpsLog);
        u[3] += a.w * __logf(a.w + kEpsLog);
        u[4] += d.x * __logf(d.x + kEpsLog);
        u[5] += d.y * __logf(d.y + kEpsLog);
        u[6] += d.z * __logf(d.z + kEpsLog);
        u[7] += d.w * __logf(d.w + kEpsLog);
    }
    unsigned long long key[8];
    #pragma unroll
    for (int i = 0; i < 8; ++i) key[i] = packKey(u[i], (unsigned int)(j0 + i));

    // ---- per-wave top-8 (no barriers): 8 rounds of wave argmax + removal ----
    __shared__ unsigned long long waveCand[4][kMaxS];
    #pragma unroll
    for (int r = 0; r < kMaxS; ++r) {
        unsigned long long my = key[0];
        #pragma unroll
        for (int i = 1; i < 8; ++i) my = u64max(my, key[i]);
        unsigned long long w = waveMax64(my);
        if (lane == 0) waveCand[wave][r] = w;
        #pragma unroll
        for (int i = 0; i < 8; ++i) if (key[i] == w) key[i] = 0ull;
    }
    __syncthreads();                      // the ONLY block barrier
    if (t >= 64) return;                  // waves 1..3 done

    // ---- wave 0: merge 4x8 wave candidates -> chunk top-8 -> global ----
    unsigned long long mine = (lane < 4 * kMaxS) ? waveCand[lane >> 3][lane & 7] : 0ull;
    unsigned long long* myCand = cand + (size_t)blockIdx.x * kMaxS;
    #pragma unroll
    for (int r = 0; r < kMaxS; ++r) {
        unsigned long long w = waveMax64(mine);
        if (lane == 0) myCand[r] = w;
        if (mine == w) mine = 0ull;
    }

    // ---- elect per-batch merger (device-scope last-block pattern) ----
    __threadfence();
    unsigned int old = 0;
    if (lane == 0) old = atomicAdd(&batch_ctr[b], 1u);
    old = (unsigned int)__shfl((int)old, 0, 64);
    if (old != (unsigned int)(kNChunk - 1)) return;
    __threadfence();

    // ---- merge this batch's 32*8 = 256 candidates (4 per lane) ----
    const unsigned long long* bc = cand + (size_t)b * kNChunk * kMaxS;
    unsigned long long c0 = bc[lane], c1 = bc[lane + 64],
                       c2 = bc[lane + 128], c3 = bc[lane + 192];
    int topPix[kMaxS];
    #pragma unroll
    for (int r = 0; r < kMaxS; ++r) {
        unsigned long long m2 = u64max(u64max(c0, c1), u64max(c2, c3));
        unsigned long long w = waveMax64(m2);
        topPix[r] = (int)(~(unsigned int)w);
        if (c0 == w) c0 = 0ull;
        if (c1 == w) c1 = 0ull;
        if (c2 == w) c2 = 0ull;
        if (c3 == w) c3 = 0ull;
    }

    // ---- gather 3 views x S vectors (lane = feature dim d), normalize, loss ----
    int idx0 = idxp[0];
    idx0 = idx0 < 0 ? 0 : (idx0 > 2 ? 2 : idx0);
    const int v1 = (idx0 == 0) ? 1 : 0;
    const int v2 = (idx0 == 2) ? 1 : 2;

    float cv[kMaxS], ap[kMaxS];
    #pragma unroll
    for (int s = 0; s < kMaxS; ++s) {
        cv[s] = 0.f; ap[s] = 0.f;
        if (s < S) {
            const size_t off = (size_t)lane * kHW + (size_t)(unsigned int)topPix[s];
            float c  = proj[((size_t)(idx0 * kB + b) * kD) * kHW + off];
            float x1 = proj[((size_t)(v1  * kB + b) * kD) * kHW + off];
            float x2 = proj[((size_t)(v2  * kB + b) * kD) * kHW + off];
            c  = c  / fmaxf(sqrtf(wave_sum(c * c)),   kEpsNorm);
            x1 = x1 / fmaxf(sqrtf(wave_sum(x1 * x1)), kEpsNorm);
            x2 = x2 / fmaxf(sqrtf(wave_sum(x2 * x2)), kEpsNorm);
            cv[s] = c; ap[s] = x1 + x2;
        }
    }
    // positive: exp((c.p1 + c.p2)/tau)
    float pl[kMaxS];
    #pragma unroll
    for (int s = 0; s < kMaxS; ++s) {
        pl[s] = 0.f;
        if (s < S) pl[s] = expf(wave_sum(cv[s] * ap[s]) / kTau);
    }
    // negatives via symmetry: neg[j] = sum_{i!=j} exp(c_i.c_j/tau)
    float neg[kMaxS];
    #pragma unroll
    for (int s = 0; s < kMaxS; ++s) neg[s] = 0.f;
    #pragma unroll
    for (int i = 0; i < kMaxS; ++i) {
        if (i < S) {
            #pragma unroll
            for (int j = i + 1; j < kMaxS; ++j) {
                if (j < S) {
                    const float e = expf(wave_sum(cv[i] * cv[j]) / kTau);
                    neg[i] += e; neg[j] += e;
                }
            }
        }
    }
    float acc = 0.f;
    #pragma unroll
    for (int s = 0; s < kMaxS; ++s)
        if (s < S) acc += -logf(pl[s] / (pl[s] + neg[s] + kEpsDen));
    if (lane == 0) per_b[b] = acc / (float)S;

    // ---- last merger overall: deterministic serial final sum ----
    __threadfence();
    unsigned int o2 = 0;
    if (lane == 0) o2 = atomicAdd(done_ctr, 1u);
    o2 = (unsigned int)__shfl((int)o2, 0, 64);
    if (o2 == (unsigned int)(kB - 1) && lane == 0) {
        __threadfence();
        float s = 0.f;
        for (int i = 0; i < kB; ++i) s += per_b[i];
        out[0] = s / (float)kB;
    }
}

extern "C" void kernel_launch(void* const* d_in, const int* in_sizes, int n_in,
                              void* d_out, int out_size, void* d_ws, size_t ws_size,
                              hipStream_t stream) {
    const float* pred = (const float*)d_in[0];
    const float* proj = (const float*)d_in[1];
    // d_in[2] mask, d_in[3] pseudo_label: unused by the reference
    const int* idxp  = (const int*)d_in[4];
    const int* snump = (const int*)d_in[5];
    float* out = (float*)d_out;

    char* ws = (char*)d_ws;
    unsigned int* batch_ctr = (unsigned int*)ws;            // 24 u32
    unsigned int* done_ctr  = (unsigned int*)(ws + 96);     // 1 u32 (pad to 128)
    unsigned long long* cand = (unsigned long long*)(ws + 128);        // 768*8 u64
    float* per_b = (float*)(ws + 128 + (size_t)kB * kNChunk * kMaxS * 8);  // 24 f32

    hipMemsetAsync(ws, 0, 128, stream);   // zero counters (captured as graph node)
    k_fused<<<kB * kNChunk, 256, 0, stream>>>(pred, proj, idxp, snump,
                                              batch_ctr, done_ctr, cand, per_b, out);
}

// Round 3
// 29.080 us; speedup vs baseline: 2.1767x; 2.1767x over previous
//
#include <hip/hip_runtime.h>
#include <float.h>
#include <limits.h>
#include <math.h>

// Fixed problem shapes
constexpr int kB = 24;
constexpr int kC = 4;
constexpr int kHW = 65536;              // 256*256
constexpr int kD = 64;
constexpr int kNChunk = 32;
constexpr int kChunk = kHW / kNChunk;   // 2048 pixels per chunk-block
constexpr int kMaxS = 8;                // supports sample_num <= 8 (actual 5)
constexpr float kTau = 0.07f;
constexpr float kEpsLog = 1e-6f;
constexpr float kEpsDen = 1e-8f;
constexpr float kEpsNorm = 1e-12f;

// ---- packed ordering key: high32 = monotone-mapped float (desc), low32 = ~pix (idx asc) ----
__device__ __forceinline__ unsigned long long packKey(float v, unsigned int pix) {
    unsigned int x = __float_as_uint(v);
    unsigned int m = (x & 0x80000000u) ? ~x : (x | 0x80000000u);  // order-preserving map
    return ((unsigned long long)m << 32) | (unsigned long long)(~pix);
}

__device__ __forceinline__ unsigned long long u64max(unsigned long long a, unsigned long long b) {
    return a > b ? a : b;
}

__device__ __forceinline__ unsigned long long shfl_xor_u64(unsigned long long k, int m) {
    int lo = __shfl_xor((int)(unsigned int)k, m, 64);
    int hi = __shfl_xor((int)(unsigned int)(k >> 32), m, 64);
    return ((unsigned long long)(unsigned int)hi << 32) | (unsigned long long)(unsigned int)lo;
}

__device__ __forceinline__ unsigned long long waveMax64(unsigned long long k) {
    #pragma unroll
    for (int o = 32; o > 0; o >>= 1) k = u64max(k, shfl_xor_u64(k, o));
    return k;
}

__device__ __forceinline__ float wave_sum(float x) {
    #pragma unroll
    for (int o = 32; o > 0; o >>= 1) x += __shfl_xor(x, o, 64);
    return x;
}

// ---------------------------------------------------------------------------
// K1: per (batch, chunk) top-8 of unc[j] = sum_c x*log(x+eps).
// Wave-level u64-key argmax; exactly ONE __syncthreads per block.
// grid: kB*kNChunk blocks x 256 threads.
// ---------------------------------------------------------------------------
__global__ __launch_bounds__(256) void k_topk(
        const float* __restrict__ pred,
        unsigned long long* __restrict__ cand) {
    const int t = threadIdx.x;
    const int lane = t & 63;
    const int wave = t >> 6;
    const int b = blockIdx.x / kNChunk;
    const int chunk = blockIdx.x % kNChunk;
    const int j0 = chunk * kChunk + t * 8;              // 8 consecutive pixels/thread
    const float* pb = pred + (size_t)b * kC * kHW + j0;

    float u[8];
    #pragma unroll
    for (int i = 0; i < 8; ++i) u[i] = 0.f;
    #pragma unroll
    for (int c = 0; c < kC; ++c) {
        float4 a = *reinterpret_cast<const float4*>(pb + (size_t)c * kHW);
        float4 d = *reinterpret_cast<const float4*>(pb + (size_t)c * kHW + 4);
        u[0] += a.x * __logf(a.x + kEpsLog);
        u[1] += a.y * __logf(a.y + kEpsLog);
        u[2] += a.z * __logf(a.z + kEpsLog);
        u[3] += a.w * __logf(a.w + kEpsLog);
        u[4] += d.x * __logf(d.x + kEpsLog);
        u[5] += d.y * __logf(d.y + kEpsLog);
        u[6] += d.z * __logf(d.z + kEpsLog);
        u[7] += d.w * __logf(d.w + kEpsLog);
    }
    unsigned long long key[8];
    #pragma unroll
    for (int i = 0; i < 8; ++i) key[i] = packKey(u[i], (unsigned int)(j0 + i));

    // per-wave top-8 (no barriers): 8 rounds of wave argmax + removal
    __shared__ unsigned long long waveCand[4][kMaxS];
    #pragma unroll
    for (int r = 0; r < kMaxS; ++r) {
        unsigned long long my = key[0];
        #pragma unroll
        for (int i = 1; i < 8; ++i) my = u64max(my, key[i]);
        unsigned long long w = waveMax64(my);
        if (lane == 0) waveCand[wave][r] = w;
        #pragma unroll
        for (int i = 0; i < 8; ++i) if (key[i] == w) key[i] = 0ull;
    }
    __syncthreads();                      // the only block barrier
    if (t >= 64) return;

    // wave 0: merge 4x8 wave candidates -> chunk top-8 -> global
    unsigned long long mine = (lane < 4 * kMaxS) ? waveCand[lane >> 3][lane & 7] : 0ull;
    unsigned long long* myCand = cand + (size_t)blockIdx.x * kMaxS;
    #pragma unroll
    for (int r = 0; r < kMaxS; ++r) {
        unsigned long long w = waveMax64(mine);
        if (lane == 0) myCand[r] = w;
        if (mine == w) mine = 0ull;
    }
}

// ---------------------------------------------------------------------------
// K2: per batch (24 blocks x 1 wave): merge 32x8 candidates -> top-S pixels,
// gather 3 views' vectors (lane = feature dim), normalize, contrastive loss.
// All 3*S scattered loads issued before any reduction (one latency hit).
// ---------------------------------------------------------------------------
__global__ __launch_bounds__(64) void k_loss(
        const float* __restrict__ proj, const int* __restrict__ idxp,
        const int* __restrict__ snum, const unsigned long long* __restrict__ cand,
        float* __restrict__ per_b) {
    int S = snum[0];
    S = S < 1 ? 1 : (S > kMaxS ? kMaxS : S);
    const int b = blockIdx.x;
    const int lane = threadIdx.x;

    // merge this batch's 32*8 = 256 candidates (4 per lane)
    const unsigned long long* bc = cand + (size_t)b * kNChunk * kMaxS;
    unsigned long long c0 = bc[lane], c1 = bc[lane + 64],
                       c2 = bc[lane + 128], c3 = bc[lane + 192];
    int topPix[kMaxS];
    #pragma unroll
    for (int r = 0; r < kMaxS; ++r) {
        unsigned long long m2 = u64max(u64max(c0, c1), u64max(c2, c3));
        unsigned long long w = waveMax64(m2);
        topPix[r] = (int)(~(unsigned int)w);
        if (c0 == w) c0 = 0ull;
        if (c1 == w) c1 = 0ull;
        if (c2 == w) c2 = 0ull;
        if (c3 == w) c3 = 0ull;
    }

    int idx0 = idxp[0];
    idx0 = idx0 < 0 ? 0 : (idx0 > 2 ? 2 : idx0);
    const int v1 = (idx0 == 0) ? 1 : 0;
    const int v2 = (idx0 == 2) ? 1 : 2;

    // issue ALL scattered loads first (independent -> one vmcnt wait)
    float cc[kMaxS], x1[kMaxS], x2[kMaxS];
    #pragma unroll
    for (int s = 0; s < kMaxS; ++s) {
        cc[s] = 0.f; x1[s] = 0.f; x2[s] = 0.f;
        if (s < S) {
            const size_t off = (size_t)lane * kHW + (size_t)(unsigned int)topPix[s];
            cc[s] = proj[((size_t)(idx0 * kB + b) * kD) * kHW + off];
            x1[s] = proj[((size_t)(v1  * kB + b) * kD) * kHW + off];
            x2[s] = proj[((size_t)(v2  * kB + b) * kD) * kHW + off];
        }
    }
    // L2-normalize (15 independent reduction chains -> compiler interleaves)
    float cv[kMaxS], ap[kMaxS];
    #pragma unroll
    for (int s = 0; s < kMaxS; ++s) {
        cv[s] = 0.f; ap[s] = 0.f;
        if (s < S) {
            const float c  = cc[s] / fmaxf(sqrtf(wave_sum(cc[s] * cc[s])), kEpsNorm);
            const float a1 = x1[s] / fmaxf(sqrtf(wave_sum(x1[s] * x1[s])), kEpsNorm);
            const float a2 = x2[s] / fmaxf(sqrtf(wave_sum(x2[s] * x2[s])), kEpsNorm);
            cv[s] = c; ap[s] = a1 + a2;
        }
    }
    // positive: exp((c.p1 + c.p2)/tau)
    float pl[kMaxS];
    #pragma unroll
    for (int s = 0; s < kMaxS; ++s) {
        pl[s] = 0.f;
        if (s < S) pl[s] = expf(wave_sum(cv[s] * ap[s]) / kTau);
    }
    // negatives via symmetry: neg[j] = sum_{i!=j} exp(c_i.c_j/tau)
    float neg[kMaxS];
    #pragma unroll
    for (int s = 0; s < kMaxS; ++s) neg[s] = 0.f;
    #pragma unroll
    for (int i = 0; i < kMaxS; ++i) {
        if (i < S) {
            #pragma unroll
            for (int j = i + 1; j < kMaxS; ++j) {
                if (j < S) {
                    const float e = expf(wave_sum(cv[i] * cv[j]) / kTau);
                    neg[i] += e; neg[j] += e;
                }
            }
        }
    }
    float acc = 0.f;
    #pragma unroll
    for (int s = 0; s < kMaxS; ++s)
        if (s < S) acc += -logf(pl[s] / (pl[s] + neg[s] + kEpsDen));
    if (lane == 0) per_b[b] = acc / (float)S;
}

// ---------------------------------------------------------------------------
// K3: deterministic serial final reduction (fixed fp order)
// ---------------------------------------------------------------------------
__global__ void k_finalize(const float* __restrict__ per_b, float* __restrict__ out) {
    if (threadIdx.x == 0 && blockIdx.x == 0) {
        float s = 0.f;
        for (int b = 0; b < kB; ++b) s += per_b[b];
        out[0] = s / (float)kB;
    }
}

extern "C" void kernel_launch(void* const* d_in, const int* in_sizes, int n_in,
                              void* d_out, int out_size, void* d_ws, size_t ws_size,
                              hipStream_t stream) {
    const float* pred = (const float*)d_in[0];
    const float* proj = (const float*)d_in[1];
    // d_in[2] mask, d_in[3] pseudo_label: unused by the reference
    const int* idxp  = (const int*)d_in[4];
    const int* snump = (const int*)d_in[5];
    float* out = (float*)d_out;

    char* ws = (char*)d_ws;
    unsigned long long* cand = (unsigned long long*)ws;                 // 768*8 u64
    float* per_b = (float*)(ws + (size_t)kB * kNChunk * kMaxS * 8);     // 24 f32

    k_topk<<<kB * kNChunk, 256, 0, stream>>>(pred, cand);
    k_loss<<<kB, 64, 0, stream>>>(proj, idxp, snump, cand, per_b);
    k_finalize<<<1, 64, 0, stream>>>(per_b, out);
}